// Round 1
// baseline (389.922 us; speedup 1.0000x reference)
//
#include <hip/hip_runtime.h>

// Problem constants
#define HDIM 256
#define WDIM 1216
#define HWC  (HDIM*WDIM)     // 311296
#define NPTS 40000
#define KNN  9
#define CCH  64
#define PIXR 256             // index range of pixel coords (0..255)

typedef float v2f __attribute__((ext_vector_type(2)));

static __device__ __forceinline__ v2f mk2(float a, float b) { v2f r; r.x = a; r.y = b; return r; }

// ---------------------------------------------------------------------------
// Kernel 1: transpose the accessed feature subregion CHW -> (iy,ix,c), ix<256
// feat_t[(iy*256+ix)*64 + c] = feat[c*HW + iy*W + ix]
// ---------------------------------------------------------------------------
__global__ void transpose_feat(const float* __restrict__ feat, float* __restrict__ feat_t) {
    int tid = blockIdx.x * 256 + threadIdx.x;    // 256*256*64 = 4,194,304 threads
    int c  = tid & 63;
    int ix = (tid >> 6) & 255;
    int iy = tid >> 14;
    feat_t[tid] = feat[c * HWC + iy * WDIM + ix];
}

// ---------------------------------------------------------------------------
// Kernel 2: last-wins winner per output pixel (numpy fancy-assignment semantics)
// ---------------------------------------------------------------------------
__global__ void winner_k(const int* __restrict__ pix, int* __restrict__ winner) {
    int n = blockIdx.x * 256 + threadIdx.x;
    if (n < NPTS) {
        int px = pix[2 * n];
        int py = pix[2 * n + 1];
        atomicMax(&winner[py * PIXR + px], n);
    }
}

// ---------------------------------------------------------------------------
// Kernel 3: main fused kernel. Wave per point, lane = channel c.
//  - MLP 3->32 (relu) ->64 (relu) per neighbor (hmid redundant per lane, j-outer)
//  - weighted gather-sum over 9 neighbors -> msg[c]
//  - 1x1 conv via msg broadcast (LDS b128) x conv row (registers)
//  - BN partial sums -> block reduce -> atomicAdd
// Grid: 625 blocks x 256 threads; each wave handles 16 points.
// ---------------------------------------------------------------------------
__global__ __launch_bounds__(256, 2) void main_k(
    const float* __restrict__ feat_t,   // [256*256, 64]
    const float* __restrict__ diff,     // [N, 9, 3]
    const int*   __restrict__ nnpix,    // [N, 9, 2]
    const float* __restrict__ W1,       // [3, 32]
    const float* __restrict__ b1,       // [32]
    const float* __restrict__ W2,       // [32, 64]
    const float* __restrict__ b2,       // [64]
    const float* __restrict__ conv_w,   // [64, 64] (out, in)
    const float* __restrict__ conv_b,   // [64]
    float* __restrict__ y_buf,          // [N, 64] pre-BN output
    float* __restrict__ sums)           // [128]: sum(y), sum(y^2) per channel
{
    __shared__ float msg_lds[4][64];
    __shared__ float r1[4][64];
    __shared__ float r2[4][64];

    const int c = threadIdx.x & 63;
    const int w = __builtin_amdgcn_readfirstlane(threadIdx.x >> 6);   // wave id, scalar

    // --- persistent per-lane preloads (loop-invariant across all 16 points) ---
    float w2col[32];                       // W2[:, c]
#pragma unroll
    for (int j = 0; j < 32; ++j) w2col[j] = W2[j * 64 + c];

    float4 cw[16];                         // conv_w[c, :]
    const float4* cwrow = (const float4*)(conv_w + c * 64);
#pragma unroll
    for (int q = 0; q < 16; ++q) cw[q] = cwrow[q];

    const float b2c = b2[c];
    const float cbc = conv_b[c];

    float s1 = 0.f, s2 = 0.f;

    for (int g = 0; g < 16; ++g) {
        const int n = (blockIdx.x * 16 + g) * 4 + w;   // scalar point index

        // --- issue gather loads early (latency hidden under MLP compute) ---
        const int* qi = nnpix + n * 18;
        float fval[KNN];
#pragma unroll
        for (int k = 0; k < KNN; ++k) {
            int ix = qi[2 * k];
            int iy = qi[2 * k + 1];
            fval[k] = feat_t[(iy * PIXR + ix) * 64 + c];
        }

        // --- load 9x3 offsets, packed in k-pairs for v_pk_fma_f32 ---
        const float* pp = diff + n * 27;
        v2f P0[4], P1[4], P2[4];
#pragma unroll
        for (int kp = 0; kp < 4; ++kp) {
            P0[kp] = mk2(pp[6 * kp + 0], pp[6 * kp + 3]);
            P1[kp] = mk2(pp[6 * kp + 1], pp[6 * kp + 4]);
            P2[kp] = mk2(pp[6 * kp + 2], pp[6 * kp + 5]);
        }
        const float p0t = pp[24], p1t = pp[25], p2t = pp[26];

        v2f acc2[4];
#pragma unroll
        for (int kp = 0; kp < 4; ++kp) acc2[kp] = mk2(b2c, b2c);
        float acc8 = b2c;

        // --- MLP: j outer (W1/b1 wave-uniform -> s_loads), k inner ---
#pragma unroll
        for (int j = 0; j < 32; ++j) {
            const float w10 = W1[j], w11 = W1[32 + j], w12 = W1[64 + j], bj = b1[j];
            const float w2v = w2col[j];
            const v2f w10p = mk2(w10, w10), w11p = mk2(w11, w11), w12p = mk2(w12, w12);
            const v2f bjp = mk2(bj, bj), w2p = mk2(w2v, w2v);
#pragma unroll
            for (int kp = 0; kp < 4; ++kp) {
                v2f hm = P0[kp] * w10p + P1[kp] * w11p + P2[kp] * w12p + bjp;
                hm = __builtin_elementwise_max(hm, mk2(0.f, 0.f));
                acc2[kp] += hm * w2p;
            }
            float hm8 = fmaf(p0t, w10, fmaf(p1t, w11, fmaf(p2t, w12, bj)));
            hm8 = fmaxf(hm8, 0.f);
            acc8 = fmaf(hm8, w2v, acc8);
        }

        // --- weighted neighbor sum: msg[c] = sum_k relu(wts) * f ---
        float wk[KNN];
        wk[0] = acc2[0].x; wk[1] = acc2[0].y; wk[2] = acc2[1].x; wk[3] = acc2[1].y;
        wk[4] = acc2[2].x; wk[5] = acc2[2].y; wk[6] = acc2[3].x; wk[7] = acc2[3].y;
        wk[8] = acc8;
        float msg = 0.f;
#pragma unroll
        for (int k = 0; k < KNN; ++k) msg = fmaf(fmaxf(wk[k], 0.f), fval[k], msg);

        // --- 1x1 conv: y[c] = conv_b[c] + sum_c' msg[c'] * conv_w[c,c'] ---
        msg_lds[w][c] = msg;
        __syncthreads();
        float y = cbc;
        const float4* ml = (const float4*)msg_lds[w];
#pragma unroll
        for (int q = 0; q < 16; ++q) {
            float4 m4 = ml[q];
            float4 c4 = cw[q];
            y = fmaf(m4.x, c4.x, y);
            y = fmaf(m4.y, c4.y, y);
            y = fmaf(m4.z, c4.z, y);
            y = fmaf(m4.w, c4.w, y);
        }
        __syncthreads();

        s1 += y;
        s2 = fmaf(y, y, s2);
        y_buf[n * 64 + c] = y;
    }

    // --- block reduction of BN partials, one atomicAdd pair per lane of wave 0 ---
    r1[w][c] = s1;
    r2[w][c] = s2;
    __syncthreads();
    if (w == 0) {
        float a  = r1[0][c] + r1[1][c] + r1[2][c] + r1[3][c];
        float bb = r2[0][c] + r2[1][c] + r2[2][c] + r2[3][c];
        atomicAdd(&sums[c], a);
        atomicAdd(&sums[64 + c], bb);
    }
}

// ---------------------------------------------------------------------------
// Kernel 4: fold BN stats into per-channel affine: A = gamma*rstd, B = beta - mean*A
// ---------------------------------------------------------------------------
__global__ void stats_k(const float* __restrict__ sums, const float* __restrict__ gamma,
                        const float* __restrict__ beta, float* __restrict__ ab) {
    int c = threadIdx.x;
    const float inv_n = 1.f / (float)NPTS;
    float mean = sums[c] * inv_n;
    float var  = sums[64 + c] * inv_n - mean * mean;
    float rstd = rsqrtf(var + 1e-5f);
    float A = gamma[c] * rstd;
    ab[c] = A;
    ab[64 + c] = beta[c] - mean * A;
}

// ---------------------------------------------------------------------------
// Kernel 5: BN apply + relu + last-wins scatter into [C,H,W] output
// ---------------------------------------------------------------------------
__global__ void apply_k(const float* __restrict__ y_buf, const float* __restrict__ ab,
                        const int* __restrict__ pix, const int* __restrict__ winner,
                        float* __restrict__ out) {
    int tid = blockIdx.x * 256 + threadIdx.x;   // N*64 = 2,560,000 threads
    int n = tid >> 6;
    int c = tid & 63;
    float y = y_buf[tid];
    float v = fmaf(ab[c], y, ab[64 + c]);
    v = fmaxf(v, 0.f);
    int px = pix[2 * n];
    int py = pix[2 * n + 1];
    if (winner[py * PIXR + px] == n) {
        out[c * HWC + py * WDIM + px] = v;
    }
}

// ---------------------------------------------------------------------------
extern "C" void kernel_launch(void* const* d_in, const int* in_sizes, int n_in,
                              void* d_out, int out_size, void* d_ws, size_t ws_size,
                              hipStream_t stream) {
    const float* feat   = (const float*)d_in[0];   // [1,64,256,1216]
    const float* diff   = (const float*)d_in[1];   // [1,40000,9,3]
    const int*   pix    = (const int*)  d_in[2];   // [1,40000,2]
    const int*   nnpix  = (const int*)  d_in[3];   // [1,40000,9,2]
    const float* W1     = (const float*)d_in[4];   // [3,32]
    const float* b1v    = (const float*)d_in[5];   // [32]
    const float* W2     = (const float*)d_in[6];   // [32,64]
    const float* b2v    = (const float*)d_in[7];   // [64]
    const float* conv_w = (const float*)d_in[8];   // [64,64]
    const float* conv_b = (const float*)d_in[9];   // [64]
    const float* gamma  = (const float*)d_in[10];  // [64]
    const float* beta   = (const float*)d_in[11];  // [64]
    float* out = (float*)d_out;

    // workspace layout (bytes):
    //   feat_t : 0          .. 16777216   (256*256*64 f32)
    //   y_buf  : 16777216   .. 27017216   (40000*64 f32)
    //   sums   : 27017216   .. 27017728   (128 f32)
    //   ab     : 27017728   .. 27018240   (128 f32)
    //   winner : 27018240   .. 27280384   (256*256 i32)
    char* ws = (char*)d_ws;
    float* feat_t = (float*)(ws);
    float* y_buf  = (float*)(ws + 16777216);
    float* sums   = (float*)(ws + 27017216);
    float* ab     = (float*)(ws + 27017728);
    int*   winner = (int*)  (ws + 27018240);

    hipMemsetAsync(d_out, 0, (size_t)out_size * sizeof(float), stream);
    hipMemsetAsync(sums, 0, 128 * sizeof(float), stream);
    hipMemsetAsync(winner, 0xFF, PIXR * PIXR * sizeof(int), stream);  // -1

    transpose_feat<<<16384, 256, 0, stream>>>(feat, feat_t);
    winner_k<<<(NPTS + 255) / 256, 256, 0, stream>>>(pix, winner);
    main_k<<<625, 256, 0, stream>>>(feat_t, diff, nnpix, W1, b1v, W2, b2v,
                                    conv_w, conv_b, y_buf, sums);
    stats_k<<<1, 64, 0, stream>>>(sums, gamma, beta, ab);
    apply_k<<<NPTS * CCH / 256, 256, 0, stream>>>(y_buf, ab, pix, winner, out);
}